// Round 1
// baseline (196.308 us; speedup 1.0000x reference)
//
#include <hip/hip_runtime.h>
#include <cstdint>

// Fused single-head attention, B=4 S=2048 D=1024, fp32 in/out, bf16 MFMA compute.
// Pipeline: cast/pack -> QKV GEMM (v transposed) -> scores GEMM -> softmax -> PV GEMM.

typedef unsigned short u16;
typedef __attribute__((ext_vector_type(4))) float f32x4;
typedef __attribute__((ext_vector_type(8))) __bf16 bf16x8;

#define AS1(p) ((const __attribute__((address_space(1))) void*)(p))
#define AS3(p) ((__attribute__((address_space(3))) void*)(p))

#define SEQ 2048
#define DM 1024
#define NB 4

// ---------- bf16 bit helpers (avoid header type drift) ----------
__device__ __forceinline__ u16 f2b(float f) {
  uint32_t u = __builtin_bit_cast(uint32_t, f);
  u += 0x7FFFu + ((u >> 16) & 1u);   // RNE
  return (u16)(u >> 16);
}
__device__ __forceinline__ float b2f(uint32_t bits16) {
  return __builtin_bit_cast(float, bits16 << 16);
}

// ---------- converts ----------
__global__ __launch_bounds__(256) void cvt_x_kernel(const float* __restrict__ x,
                                                    u16* __restrict__ xb) {
  int i = (blockIdx.x * 256 + threadIdx.x) * 4;
  float4 v = *(const float4*)(x + i);
  ushort4 o;
  o.x = f2b(v.x); o.y = f2b(v.y); o.z = f2b(v.z); o.w = f2b(v.w);
  *(ushort4*)(xb + i) = o;
}

__global__ __launch_bounds__(256) void pack_w_kernel(const float* __restrict__ Wq,
                                                     const float* __restrict__ Wk,
                                                     const float* __restrict__ Wv,
                                                     u16* __restrict__ wcat) {
  int i = (blockIdx.x * 256 + threadIdx.x) * 4;   // over 3*2^20 elems
  const float* src;
  int j;
  if (i < (1 << 20))      { src = Wq; j = i; }
  else if (i < (2 << 20)) { src = Wk; j = i - (1 << 20); }
  else                    { src = Wv; j = i - (2 << 20); }
  float4 v = *(const float4*)(src + j);
  ushort4 o;
  o.x = f2b(v.x); o.y = f2b(v.y); o.z = f2b(v.z); o.w = f2b(v.w);
  *(ushort4*)(wcat + i) = o;
}

// ---------- GEMM core: C[128x128] += A[128xK] * Bt[128xK]^T, bf16, fp32 acc ----------
// LDS tile: [128 rows][64 cols] bf16 = 16 KB, XOR-swizzled 16B chunks within each
// 128B row: physical_chunk = logical_chunk ^ (row & 7).  global_load_lds writes the
// LDS linearly (wave base + lane*16) so the *global source* is inverse-swizzled
// (rule 21c), and ds_read applies the same XOR.
#define BK 64

__device__ __forceinline__ void stage_tile(const u16* __restrict__ g, int ld,
                                           char* lds, int tid) {
  int w = tid >> 6, l = tid & 63;
#pragma unroll
  for (int p = 0; p < 4; ++p) {
    int o  = p * 4096 + w * 1024 + l * 16;   // linear LDS byte offset this lane fills
    int r  = o >> 7;                          // row (128B per row)
    int pc = (o >> 4) & 7;                    // physical 16B chunk
    int lc = pc ^ (r & 7);                    // logical chunk to fetch
    const u16* src = g + r * ld + lc * 8;
    char* dst = lds + p * 4096 + w * 1024;    // wave-uniform base; HW adds lane*16
    __builtin_amdgcn_global_load_lds(AS1(src), AS3(dst), 16, 0, 0);
  }
}

__device__ __forceinline__ bf16x8 read_frag(const char* lds, int row, int kk) {
  int lc  = kk >> 3;
  int off = row * 128 + ((lc ^ (row & 7)) << 4);
  return *(const bf16x8*)(lds + off);
}

__device__ __forceinline__ void gemm_core(const u16* __restrict__ A,
                                          const u16* __restrict__ Bt,
                                          int K, int lda, int ldb,
                                          char* ldsA, char* ldsB,
                                          f32x4 acc[4][4], int tid) {
  int w = tid >> 6, l = tid & 63;
  int wm = (w >> 1) * 64, wn = (w & 1) * 64;
  int fr = l & 15, fk = (l >> 4) * 8;
  for (int k0 = 0; k0 < K; k0 += BK) {
    stage_tile(A + k0, lda, ldsA, tid);
    stage_tile(Bt + k0, ldb, ldsB, tid);
    __syncthreads();
#pragma unroll
    for (int ks = 0; ks < 2; ++ks) {
      bf16x8 af[4], bfr[4];
#pragma unroll
      for (int m = 0; m < 4; ++m) af[m]  = read_frag(ldsA, wm + m * 16 + fr, ks * 32 + fk);
#pragma unroll
      for (int n = 0; n < 4; ++n) bfr[n] = read_frag(ldsB, wn + n * 16 + fr, ks * 32 + fk);
#pragma unroll
      for (int m = 0; m < 4; ++m)
#pragma unroll
        for (int n = 0; n < 4; ++n)
          acc[m][n] = __builtin_amdgcn_mfma_f32_16x16x32_bf16(af[m], bfr[n], acc[m][n], 0, 0, 0);
    }
    __syncthreads();
  }
}

#define ZERO_ACC(acc)                                     \
  _Pragma("unroll") for (int m_ = 0; m_ < 4; ++m_)        \
  _Pragma("unroll") for (int n_ = 0; n_ < 4; ++n_)        \
  _Pragma("unroll") for (int j_ = 0; j_ < 4; ++j_)        \
      acc[m_][n_][j_] = 0.f;

// ---------- QKV GEMM: [8192 x 3072] = xb[8192x1024] * wcat[3072x1024]^T + bias ----------
// n in [0,1024) -> q (row-major), [1024,2048) -> k (row-major), [2048,3072) -> v TRANSPOSED [d][s]
__global__ __launch_bounds__(256, 2) void qkv_gemm(const u16* __restrict__ xb,
                                                   const u16* __restrict__ wcat,
                                                   const float* __restrict__ bq,
                                                   const float* __restrict__ bk,
                                                   const float* __restrict__ bv,
                                                   u16* __restrict__ qb,
                                                   u16* __restrict__ kb,
                                                   u16* __restrict__ vtb) {
  __shared__ __align__(16) char lds[32768];
  int tid = threadIdx.x;
  int bm = blockIdx.y * 128, bn = blockIdx.x * 128;
  f32x4 acc[4][4];
  ZERO_ACC(acc);
  gemm_core(xb + bm * 1024, wcat + bn * 1024, 1024, 1024, 1024, lds, lds + 16384, acc, tid);
  int w = tid >> 6, l = tid & 63;
  int wm = (w >> 1) * 64, wn = (w & 1) * 64;
  int which = bn >> 10;  // uniform per block (128 | 1024)
  const float* bias = (which == 0) ? bq : (which == 1) ? bk : bv;
#pragma unroll
  for (int m = 0; m < 4; ++m)
#pragma unroll
    for (int n = 0; n < 4; ++n) {
      int col = bn + wn + n * 16 + (l & 15);
      int e = col & 1023;
      float bval = bias[e];
#pragma unroll
      for (int j = 0; j < 4; ++j) {
        int row = bm + wm + m * 16 + (l >> 4) * 4 + j;
        u16 hb = f2b(acc[m][n][j] + bval);
        if (which == 0)      qb[row * 1024 + e] = hb;
        else if (which == 1) kb[row * 1024 + e] = hb;
        else { int b = row >> 11, s = row & 2047; vtb[(b << 21) + e * 2048 + s] = hb; }
      }
    }
}

// ---------- scores GEMM per batch: sb = (q * k^T) / 32, bf16 ----------
__global__ __launch_bounds__(256, 2) void scores_gemm(const u16* __restrict__ qb,
                                                      const u16* __restrict__ kb,
                                                      u16* __restrict__ sb) {
  __shared__ __align__(16) char lds[32768];
  int tid = threadIdx.x;
  int b = blockIdx.z;
  int bm = blockIdx.y * 128, bn = blockIdx.x * 128;
  const u16* A  = qb + b * (SEQ * DM) + bm * 1024;
  const u16* Bt = kb + b * (SEQ * DM) + bn * 1024;
  f32x4 acc[4][4];
  ZERO_ACC(acc);
  gemm_core(A, Bt, 1024, 1024, 1024, lds, lds + 16384, acc, tid);
  u16* out = sb + (size_t)b * SEQ * SEQ;
  int w = tid >> 6, l = tid & 63;
  int wm = (w >> 1) * 64, wn = (w & 1) * 64;
#pragma unroll
  for (int m = 0; m < 4; ++m)
#pragma unroll
    for (int n = 0; n < 4; ++n) {
      int col = bn + wn + n * 16 + (l & 15);
#pragma unroll
      for (int j = 0; j < 4; ++j) {
        int row = bm + wm + m * 16 + (l >> 4) * 4 + j;
        out[row * 2048 + col] = f2b(acc[m][n][j] * 0.03125f);
      }
    }
}

// ---------- row softmax: 2048-wide rows, bf16 in, bf16 out ----------
__global__ __launch_bounds__(256) void softmax_k(const u16* __restrict__ sb,
                                                 u16* __restrict__ pb) {
  __shared__ float red[8];
  int row = blockIdx.x;
  const u16* src = sb + (size_t)row * 2048;
  u16* dst = pb + (size_t)row * 2048;
  int t = threadIdx.x;
  uint4 raw = *(const uint4*)(src + t * 8);
  uint32_t rw[4] = {raw.x, raw.y, raw.z, raw.w};
  float v[8];
#pragma unroll
  for (int q = 0; q < 4; ++q) {
    v[2 * q]     = b2f(rw[q] & 0xFFFFu);
    v[2 * q + 1] = __builtin_bit_cast(float, rw[q] & 0xFFFF0000u);
  }
  float m = v[0];
#pragma unroll
  for (int j = 1; j < 8; ++j) m = fmaxf(m, v[j]);
  for (int off = 32; off; off >>= 1) m = fmaxf(m, __shfl_xor(m, off));
  int w = t >> 6, l = t & 63;
  if (l == 0) red[w] = m;
  __syncthreads();
  m = fmaxf(fmaxf(red[0], red[1]), fmaxf(red[2], red[3]));
  float e[8], s = 0.f;
#pragma unroll
  for (int j = 0; j < 8; ++j) { e[j] = __expf(v[j] - m); s += e[j]; }
  for (int off = 32; off; off >>= 1) s += __shfl_xor(s, off);
  if (l == 0) red[4 + w] = s;
  __syncthreads();
  s = (red[4] + red[5]) + (red[6] + red[7]);
  float inv = 1.0f / s;
  uint32_t o[4];
#pragma unroll
  for (int q = 0; q < 4; ++q) {
    uint32_t lo = f2b(e[2 * q] * inv);
    uint32_t hi = f2b(e[2 * q + 1] * inv);
    o[q] = lo | (hi << 16);
  }
  *(uint4*)(dst + t * 8) = make_uint4(o[0], o[1], o[2], o[3]);
}

// ---------- PV GEMM per batch: out = pb[2048x2048] * v[2048x1024], K=2048, fp32 out ----------
__global__ __launch_bounds__(256, 2) void pv_gemm(const u16* __restrict__ pb,
                                                  const u16* __restrict__ vtb,
                                                  float* __restrict__ out) {
  __shared__ __align__(16) char lds[32768];
  int tid = threadIdx.x;
  int b = blockIdx.z;
  int bm = blockIdx.y * 128, bn = blockIdx.x * 128;
  const u16* A  = pb  + (size_t)b * SEQ * SEQ + bm * 2048;   // [2048 x 2048]
  const u16* Bt = vtb + (size_t)b * DM * SEQ  + bn * 2048;   // v^T: [1024 x 2048]
  f32x4 acc[4][4];
  ZERO_ACC(acc);
  gemm_core(A, Bt, 2048, 2048, 2048, lds, lds + 16384, acc, tid);
  float* o = out + (size_t)b * SEQ * DM;
  int w = tid >> 6, l = tid & 63;
  int wm = (w >> 1) * 64, wn = (w & 1) * 64;
#pragma unroll
  for (int m = 0; m < 4; ++m)
#pragma unroll
    for (int n = 0; n < 4; ++n) {
      int col = bn + wn + n * 16 + (l & 15);
#pragma unroll
      for (int j = 0; j < 4; ++j) {
        int row = bm + wm + m * 16 + (l >> 4) * 4 + j;
        o[row * 1024 + col] = acc[m][n][j];
      }
    }
}

// ---------- launch ----------
extern "C" void kernel_launch(void* const* d_in, const int* in_sizes, int n_in,
                              void* d_out, int out_size, void* d_ws, size_t ws_size,
                              hipStream_t stream) {
  const float* x  = (const float*)d_in[0];
  const float* Wq = (const float*)d_in[1];
  const float* bq = (const float*)d_in[2];
  const float* Wk = (const float*)d_in[3];
  const float* bk = (const float*)d_in[4];
  const float* Wv = (const float*)d_in[5];
  const float* bv = (const float*)d_in[6];
  float* out = (float*)d_out;

  char* ws = (char*)d_ws;
  // ws layout (bytes): total 140,509,184
  u16* xb   = (u16*)(ws);                 // 16 MB  bf16 x            [8192][1024]
  u16* wcat = (u16*)(ws + 16777216);      //  6 MB  bf16 Wq|Wk|Wv     [3072][1024]
  u16* qb   = (u16*)(ws + 23068672);      // 16 MB  bf16 q            [4][2048][1024]
  u16* kb   = (u16*)(ws + 39845888);      // 16 MB  bf16 k            [4][2048][1024]
  u16* vtb  = (u16*)(ws + 56623104);      // 16 MB  bf16 v^T          [4][1024][2048]
  u16* sb   = (u16*)(ws + 73400320);      // 32 MB  bf16 scores       [4][2048][2048]
  u16* pb   = (u16*)(ws + 106954752);     // 32 MB  bf16 probs        [4][2048][2048]

  cvt_x_kernel<<<8192, 256, 0, stream>>>(x, xb);
  pack_w_kernel<<<3072, 256, 0, stream>>>(Wq, Wk, Wv, wcat);
  qkv_gemm<<<dim3(24, 64), 256, 0, stream>>>(xb, wcat, bq, bk, bv, qb, kb, vtb);
  scores_gemm<<<dim3(16, 16, 4), 256, 0, stream>>>(qb, kb, sb);
  softmax_k<<<8192, 256, 0, stream>>>(sb, pb);
  pv_gemm<<<dim3(8, 16, 4), 256, 0, stream>>>(pb, vtb, out);
}